// Round 1
// baseline (3170.942 us; speedup 1.0000x reference)
//
#include <hip/hip_runtime.h>
#include <math.h>

#define BD 2
#define HD 16
#define NSEQ 8192
#define DDIM 64
#define NPROJ 7
#define KBLK 256
#define NSAMP 256
#define NBH (BD*HD)           // 32
#define NB (NSEQ/KBLK)        // 32

// ---------------------------------------------------------------------------
// Kernel A: per-key norms + per-(b,h) max norm
// ---------------------------------------------------------------------------
__global__ __launch_bounds__(256) void knorm_kernel(const float* __restrict__ key,
                                                    float* __restrict__ knorm,
                                                    float* __restrict__ kmax) {
    const int bh = blockIdx.x;
    const int tid = threadIdx.x;
    __shared__ float red[256];
    float lmax = 0.f;
    const float* kb = key + (size_t)bh * NSEQ * DDIM;
    for (int n = tid; n < NSEQ; n += 256) {
        const float4* kp = (const float4*)(kb + (size_t)n * DDIM);
        float ss = 0.f;
        #pragma unroll
        for (int j = 0; j < 16; ++j) {
            float4 t = kp[j];
            ss += t.x*t.x + t.y*t.y + t.z*t.z + t.w*t.w;
        }
        float nr = sqrtf(ss);
        knorm[bh*NSEQ + n] = nr;
        lmax = fmaxf(lmax, nr);
    }
    red[tid] = lmax;
    __syncthreads();
    for (int s = 128; s > 0; s >>= 1) {
        if (tid < s) red[tid] = fmaxf(red[tid], red[tid+s]);
        __syncthreads();
    }
    if (tid == 0) kmax[bh] = red[0];
}

// ---------------------------------------------------------------------------
// Kernel B: LSH hashes for queries (aug coord = 0) and keys (aug = sqrt(max^2-n^2))
// hash = gray(bin) = bin ^ (bin>>1); bin bit r = (dot_r > 0)
// ---------------------------------------------------------------------------
__global__ __launch_bounds__(256) void hash_kernel(const float* __restrict__ q,
                                                   const float* __restrict__ k,
                                                   const float* __restrict__ pd,
                                                   const float* __restrict__ knorm,
                                                   const float* __restrict__ kmax,
                                                   unsigned char* __restrict__ qh,
                                                   unsigned char* __restrict__ kh) {
    __shared__ float pds[(DDIM+1)*NPROJ];
    const int tid = threadIdx.x;
    for (int i = tid; i < (DDIM+1)*NPROJ; i += 256) pds[i] = pd[i];
    __syncthreads();

    const int lin = blockIdx.x * 256 + tid;     // [0, NBH*NSEQ)
    const int bh = lin / NSEQ;

    float acc[NPROJ];
    float4 xv[16];

    // ---- query hash ----
    {
        const float4* xp = (const float4*)(q + (size_t)lin * DDIM);
        #pragma unroll
        for (int j = 0; j < 16; ++j) xv[j] = xp[j];
        #pragma unroll
        for (int r = 0; r < NPROJ; ++r) acc[r] = 0.f;
        #pragma unroll
        for (int j = 0; j < 16; ++j) {
            float xs[4] = {xv[j].x, xv[j].y, xv[j].z, xv[j].w};
            #pragma unroll
            for (int c = 0; c < 4; ++c) {
                const int d = j*4 + c;
                #pragma unroll
                for (int r = 0; r < NPROJ; ++r) acc[r] += xs[c] * pds[d*NPROJ + r];
            }
        }
        int bin = 0;
        #pragma unroll
        for (int r = 0; r < NPROJ; ++r) bin |= (acc[r] > 0.f) << r;
        qh[lin] = (unsigned char)(bin ^ (bin >> 1));
    }

    // ---- key hash ----
    {
        const float4* xp = (const float4*)(k + (size_t)lin * DDIM);
        #pragma unroll
        for (int j = 0; j < 16; ++j) xv[j] = xp[j];
        #pragma unroll
        for (int r = 0; r < NPROJ; ++r) acc[r] = 0.f;
        #pragma unroll
        for (int j = 0; j < 16; ++j) {
            float xs[4] = {xv[j].x, xv[j].y, xv[j].z, xv[j].w};
            #pragma unroll
            for (int c = 0; c < 4; ++c) {
                const int d = j*4 + c;
                #pragma unroll
                for (int r = 0; r < NPROJ; ++r) acc[r] += xs[c] * pds[d*NPROJ + r];
            }
        }
        const float kn = knorm[lin];
        const float km = kmax[bh];
        const float ex = sqrtf(fmaxf(km*km - kn*kn, 0.f));
        #pragma unroll
        for (int r = 0; r < NPROJ; ++r) acc[r] += ex * pds[DDIM*NPROJ + r];
        int bin = 0;
        #pragma unroll
        for (int r = 0; r < NPROJ; ++r) bin |= (acc[r] > 0.f) << r;
        kh[lin] = (unsigned char)(bin ^ (bin >> 1));
    }
}

// ---------------------------------------------------------------------------
// Kernel C: stable counting sort by hash (128 buckets) per (b,h).
// Thread t owns bucket t. Exactly reproduces jnp.argsort(..., stable=True).
// ---------------------------------------------------------------------------
__global__ __launch_bounds__(128) void sort_kernel(const unsigned char* __restrict__ hash,
                                                   int* __restrict__ idx) {
    __shared__ unsigned int hwords[NSEQ/4];
    __shared__ int cnt[128];
    __shared__ int offs[128];
    const int bh = blockIdx.x;
    const int tid = threadIdx.x;
    const unsigned int* src = (const unsigned int*)(hash + (size_t)bh * NSEQ);
    for (int i = tid; i < NSEQ/4; i += 128) hwords[i] = src[i];
    __syncthreads();

    const unsigned int me = (unsigned int)tid;
    int c = 0;
    for (int w = 0; w < NSEQ/4; ++w) {
        unsigned int x = hwords[w];
        c += ((x & 255u) == me) + (((x >> 8) & 255u) == me)
           + (((x >> 16) & 255u) == me) + ((x >> 24) == me);
    }
    cnt[tid] = c;
    __syncthreads();
    if (tid == 0) {
        int run = 0;
        for (int b = 0; b < 128; ++b) { offs[b] = run; run += cnt[b]; }
    }
    __syncthreads();

    int off = offs[tid];
    int* dst = idx + (size_t)bh * NSEQ;
    for (int w = 0; w < NSEQ/4; ++w) {
        unsigned int x = hwords[w];
        const int n = w * 4;
        if ((x & 255u) == me)         dst[off++] = n;
        if (((x >> 8) & 255u) == me)  dst[off++] = n + 1;
        if (((x >> 16) & 255u) == me) dst[off++] = n + 2;
        if ((x >> 24) == me)          dst[off++] = n + 3;
    }
}

// ---------------------------------------------------------------------------
// Kernel D: fused block-diagonal attention + sampled residual + log-space merge.
// One block per (key-block g, bh). One thread per query row (256 rows).
// Scores are small (|s| <~ 8) so sum exp(s) directly, no max subtraction.
// Output written at the ORIGINAL query row (fuses the final un-sort).
// ---------------------------------------------------------------------------
__global__ __launch_bounds__(256) void attn_kernel(const float* __restrict__ q,
                                                   const float* __restrict__ k,
                                                   const float* __restrict__ v,
                                                   const int* __restrict__ samp,
                                                   const int* __restrict__ qidx,
                                                   const int* __restrict__ kidx,
                                                   float* __restrict__ out) {
    extern __shared__ float lds[];
    float* Ks = lds;                       // [256][64]
    float* Vs = lds + KBLK*DDIM;           // [256][64]
    int*   SB = (int*)(lds + 2*KBLK*DDIM); // [256] sampled-column block ids

    const int g = blockIdx.x, bh = blockIdx.y, tid = threadIdx.x;
    const size_t base = (size_t)bh * NSEQ * DDIM;
    const float scale = 0.125f;            // D^-0.5

    // my query row (sorted position), original row for write-back
    const int qorig = qidx[bh*NSEQ + g*KBLK + tid];
    float4 qv[16];
    {
        const float4* qp = (const float4*)(q + base + (size_t)qorig * DDIM);
        #pragma unroll
        for (int j = 0; j < 16; ++j) qv[j] = qp[j];
    }

    // ---- phase 1: stage this key-block's K,V (gathered by sorted index) ----
    {
        const int kr = kidx[bh*NSEQ + g*KBLK + tid];
        const float4* kp = (const float4*)(k + base + (size_t)kr * DDIM);
        const float4* vp = (const float4*)(v + base + (size_t)kr * DDIM);
        float4* kd = (float4*)(Ks + tid*DDIM);
        float4* vd = (float4*)(Vs + tid*DDIM);
        #pragma unroll
        for (int j = 0; j < 16; ++j) kd[j] = kp[j];
        #pragma unroll
        for (int j = 0; j < 16; ++j) vd[j] = vp[j];
    }
    __syncthreads();

    // pass A: denominator
    float l_blk = 0.f;
    for (int kk = 0; kk < KBLK; ++kk) {
        const float4* krw = (const float4*)(Ks + kk*DDIM);
        float s = 0.f;
        #pragma unroll
        for (int j = 0; j < 16; ++j) {
            float4 t = krw[j];
            s += qv[j].x*t.x + qv[j].y*t.y + qv[j].z*t.z + qv[j].w*t.w;
        }
        l_blk += __expf(s * scale);
    }
    const float lse_blk = __logf(l_blk);

    // pass B: accumulate w * V
    float4 acc[16];
    #pragma unroll
    for (int j = 0; j < 16; ++j) acc[j] = make_float4(0.f, 0.f, 0.f, 0.f);
    for (int kk = 0; kk < KBLK; ++kk) {
        const float4* krw = (const float4*)(Ks + kk*DDIM);
        float s = 0.f;
        #pragma unroll
        for (int j = 0; j < 16; ++j) {
            float4 t = krw[j];
            s += qv[j].x*t.x + qv[j].y*t.y + qv[j].z*t.z + qv[j].w*t.w;
        }
        const float w = __expf(s * scale);
        const float4* vrw = (const float4*)(Vs + kk*DDIM);
        #pragma unroll
        for (int j = 0; j < 16; ++j) {
            float4 t = vrw[j];
            acc[j].x += w*t.x; acc[j].y += w*t.y; acc[j].z += w*t.z; acc[j].w += w*t.w;
        }
    }

    __syncthreads();
    // ---- phase 2: stage sampled columns (gathered k_s/v_s rows) ----
    {
        const int sp = samp[bh*NSAMP + tid];
        SB[tid] = sp >> 8;                 // sampled sorted pos / BLOCK
        const int kr = kidx[bh*NSEQ + sp];
        const float4* kp = (const float4*)(k + base + (size_t)kr * DDIM);
        const float4* vp = (const float4*)(v + base + (size_t)kr * DDIM);
        float4* kd = (float4*)(Ks + tid*DDIM);
        float4* vd = (float4*)(Vs + tid*DDIM);
        #pragma unroll
        for (int j = 0; j < 16; ++j) kd[j] = kp[j];
        #pragma unroll
        for (int j = 0; j < 16; ++j) vd[j] = vp[j];
    }
    __syncthreads();

    // pass A2: residual denominator with coverage mask
    float l_res = 0.f;
    for (int ss = 0; ss < NSAMP; ++ss) {
        const float4* krw = (const float4*)(Ks + ss*DDIM);
        float s = 0.f;
        #pragma unroll
        for (int j = 0; j < 16; ++j) {
            float4 t = krw[j];
            s += qv[j].x*t.x + qv[j].y*t.y + qv[j].z*t.z + qv[j].w*t.w;
        }
        float e = __expf(s * scale);
        if (SB[ss] == g) e = 0.f;
        l_res += e;
    }
    const float lse_res = __logf(l_res) + 3.46573590280f;  // + log(N/SAMPLE)=log(32)
    const float cmix = 1.f / (1.f + __expf(lse_res - lse_blk));
    const float fb = cmix / l_blk;
    const float fr = (1.f - cmix) / l_res;

    #pragma unroll
    for (int j = 0; j < 16; ++j) {
        acc[j].x *= fb; acc[j].y *= fb; acc[j].z *= fb; acc[j].w *= fb;
    }

    // pass B2: accumulate residual with premultiplied factor
    for (int ss = 0; ss < NSAMP; ++ss) {
        const float4* krw = (const float4*)(Ks + ss*DDIM);
        float s = 0.f;
        #pragma unroll
        for (int j = 0; j < 16; ++j) {
            float4 t = krw[j];
            s += qv[j].x*t.x + qv[j].y*t.y + qv[j].z*t.z + qv[j].w*t.w;
        }
        float w = __expf(s * scale);
        if (SB[ss] == g) w = 0.f;
        w *= fr;
        const float4* vrw = (const float4*)(Vs + ss*DDIM);
        #pragma unroll
        for (int j = 0; j < 16; ++j) {
            float4 t = vrw[j];
            acc[j].x += w*t.x; acc[j].y += w*t.y; acc[j].z += w*t.z; acc[j].w += w*t.w;
        }
    }

    // write back at ORIGINAL query row (fused un-sort)
    float4* op = (float4*)(out + base + (size_t)qorig * DDIM);
    #pragma unroll
    for (int j = 0; j < 16; ++j) op[j] = acc[j];
}

// ---------------------------------------------------------------------------
extern "C" void kernel_launch(void* const* d_in, const int* in_sizes, int n_in,
                              void* d_out, int out_size, void* d_ws, size_t ws_size,
                              hipStream_t stream) {
    const float* q    = (const float*)d_in[0];
    const float* k    = (const float*)d_in[1];
    const float* v    = (const float*)d_in[2];
    const float* pd   = (const float*)d_in[3];
    const int*   samp = (const int*)d_in[4];
    float* out = (float*)d_out;

    char* ws = (char*)d_ws;
    float*         knorm = (float*)(ws + 0);
    float*         kmax  = (float*)(ws + 1048576);
    unsigned char* qh    = (unsigned char*)(ws + 1048704);
    unsigned char* kh    = (unsigned char*)(ws + 1310848);
    int*           qidx  = (int*)(ws + 1572992);
    int*           kidx  = (int*)(ws + 2621568);

    hipLaunchKernelGGL(knorm_kernel, dim3(NBH), dim3(256), 0, stream, k, knorm, kmax);
    hipLaunchKernelGGL(hash_kernel, dim3(NBH*NSEQ/256), dim3(256), 0, stream,
                       q, k, pd, knorm, kmax, qh, kh);
    hipLaunchKernelGGL(sort_kernel, dim3(NBH), dim3(128), 0, stream, qh, qidx);
    hipLaunchKernelGGL(sort_kernel, dim3(NBH), dim3(128), 0, stream, kh, kidx);

    const size_t lds_bytes = (size_t)(2*KBLK*DDIM)*sizeof(float) + KBLK*sizeof(int);
    hipLaunchKernelGGL(attn_kernel, dim3(NB, NBH), dim3(256), lds_bytes, stream,
                       q, k, v, samp, qidx, kidx, out);
}

// Round 2
// 336.037 us; speedup vs baseline: 9.4363x; 9.4363x over previous
//
#include <hip/hip_runtime.h>
#include <math.h>

#define BD 2
#define HD 16
#define NSEQ 8192
#define DDIM 64
#define NPROJ 7
#define KBLK 256
#define NSAMP 256
#define NBH (BD*HD)           // 32
#define NB (NSEQ/KBLK)        // 32

typedef short bf16x8 __attribute__((ext_vector_type(8)));
typedef float f32x4 __attribute__((ext_vector_type(4)));

__device__ __forceinline__ unsigned short f2bf(float f) {
    union { float f; unsigned int u; } x; x.f = f;
    unsigned int r = (x.u + 0x7FFFu + ((x.u >> 16) & 1u)) >> 16;
    return (unsigned short)r;
}
__device__ __forceinline__ float bf2f(unsigned short h) {
    union { float f; unsigned int u; } x; x.u = ((unsigned int)h) << 16;
    return x.f;
}

// ---------------------------------------------------------------------------
// Kernel A: per-key norms + per-(b,h) max norm
// ---------------------------------------------------------------------------
__global__ __launch_bounds__(256) void knorm_kernel(const float* __restrict__ key,
                                                    float* __restrict__ knorm,
                                                    float* __restrict__ kmax) {
    const int bh = blockIdx.x;
    const int tid = threadIdx.x;
    __shared__ float red[256];
    float lmax = 0.f;
    const float* kb = key + (size_t)bh * NSEQ * DDIM;
    for (int n = tid; n < NSEQ; n += 256) {
        const float4* kp = (const float4*)(kb + (size_t)n * DDIM);
        float ss = 0.f;
        #pragma unroll
        for (int j = 0; j < 16; ++j) {
            float4 t = kp[j];
            ss += t.x*t.x + t.y*t.y + t.z*t.z + t.w*t.w;
        }
        float nr = sqrtf(ss);
        knorm[bh*NSEQ + n] = nr;
        lmax = fmaxf(lmax, nr);
    }
    red[tid] = lmax;
    __syncthreads();
    for (int s = 128; s > 0; s >>= 1) {
        if (tid < s) red[tid] = fmaxf(red[tid], red[tid+s]);
        __syncthreads();
    }
    if (tid == 0) kmax[bh] = red[0];
}

// ---------------------------------------------------------------------------
// Kernel B: LSH hashes for queries (aug coord = 0) and keys (aug = sqrt(max^2-n^2))
// ---------------------------------------------------------------------------
__global__ __launch_bounds__(256) void hash_kernel(const float* __restrict__ q,
                                                   const float* __restrict__ k,
                                                   const float* __restrict__ pd,
                                                   const float* __restrict__ knorm,
                                                   const float* __restrict__ kmax,
                                                   unsigned char* __restrict__ qh,
                                                   unsigned char* __restrict__ kh) {
    __shared__ float pds[(DDIM+1)*NPROJ];
    const int tid = threadIdx.x;
    for (int i = tid; i < (DDIM+1)*NPROJ; i += 256) pds[i] = pd[i];
    __syncthreads();

    const int lin = blockIdx.x * 256 + tid;
    const int bh = lin / NSEQ;

    float acc[NPROJ];
    float4 xv[16];

    {
        const float4* xp = (const float4*)(q + (size_t)lin * DDIM);
        #pragma unroll
        for (int j = 0; j < 16; ++j) xv[j] = xp[j];
        #pragma unroll
        for (int r = 0; r < NPROJ; ++r) acc[r] = 0.f;
        #pragma unroll
        for (int j = 0; j < 16; ++j) {
            float xs[4] = {xv[j].x, xv[j].y, xv[j].z, xv[j].w};
            #pragma unroll
            for (int c = 0; c < 4; ++c) {
                const int d = j*4 + c;
                #pragma unroll
                for (int r = 0; r < NPROJ; ++r) acc[r] += xs[c] * pds[d*NPROJ + r];
            }
        }
        int bin = 0;
        #pragma unroll
        for (int r = 0; r < NPROJ; ++r) bin |= (acc[r] > 0.f) << r;
        qh[lin] = (unsigned char)(bin ^ (bin >> 1));
    }

    {
        const float4* xp = (const float4*)(k + (size_t)lin * DDIM);
        #pragma unroll
        for (int j = 0; j < 16; ++j) xv[j] = xp[j];
        #pragma unroll
        for (int r = 0; r < NPROJ; ++r) acc[r] = 0.f;
        #pragma unroll
        for (int j = 0; j < 16; ++j) {
            float xs[4] = {xv[j].x, xv[j].y, xv[j].z, xv[j].w};
            #pragma unroll
            for (int c = 0; c < 4; ++c) {
                const int d = j*4 + c;
                #pragma unroll
                for (int r = 0; r < NPROJ; ++r) acc[r] += xs[c] * pds[d*NPROJ + r];
            }
        }
        const float kn = knorm[lin];
        const float km = kmax[bh];
        const float ex = sqrtf(fmaxf(km*km - kn*kn, 0.f));
        #pragma unroll
        for (int r = 0; r < NPROJ; ++r) acc[r] += ex * pds[DDIM*NPROJ + r];
        int bin = 0;
        #pragma unroll
        for (int r = 0; r < NPROJ; ++r) bin |= (acc[r] > 0.f) << r;
        kh[lin] = (unsigned char)(bin ^ (bin >> 1));
    }
}

// ---------------------------------------------------------------------------
// Kernel C: parallel stable counting sort (128 buckets) per (b,h).
// 128 segments of 64 elems; cnt[seg][bucket] u16; column prefix -> stable.
// ---------------------------------------------------------------------------
__global__ __launch_bounds__(128) void sort_kernel(const unsigned char* __restrict__ hash,
                                                   int* __restrict__ idx) {
    __shared__ unsigned char hsh[NSEQ];
    __shared__ unsigned short cnt[128][128];
    __shared__ int base[128];
    const int bh = blockIdx.x, tid = threadIdx.x;
    const unsigned int* src = (const unsigned int*)(hash + (size_t)bh * NSEQ);
    for (int i = tid; i < NSEQ/4; i += 128) ((unsigned int*)hsh)[i] = src[i];
    for (int b = 0; b < 128; ++b) cnt[tid][b] = 0;
    __syncthreads();
    {
        const unsigned char* s = hsh + tid*64;
        for (int i = 0; i < 64; ++i) cnt[tid][s[i]]++;
    }
    __syncthreads();
    {
        int run = 0;
        for (int s = 0; s < 128; ++s) {
            int t = cnt[s][tid]; cnt[s][tid] = (unsigned short)run; run += t;
        }
        base[tid] = run;
    }
    __syncthreads();
    if (tid == 0) {
        int run = 0;
        for (int b = 0; b < 128; ++b) { int t = base[b]; base[b] = run; run += t; }
    }
    __syncthreads();
    {
        const unsigned char* s = hsh + tid*64;
        int* dst = idx + (size_t)bh * NSEQ;
        for (int i = 0; i < 64; ++i) {
            int h = s[i];
            int c = cnt[tid][h];
            cnt[tid][h] = (unsigned short)(c + 1);
            dst[base[h] + c] = tid*64 + i;
        }
    }
}

// ---------------------------------------------------------------------------
// Kernel D: MFMA fused attention.
// Per block (g,bh): 4 waves x 64 query rows. 3 phases x 4 chunks of 64 keys:
//   A: residual l_res (1-split QK), B: block-diag (2-split QK + PV, l_blk),
//   C: residual full (P pre-scaled by fr, PV into same O).
// S^T = mfma(K, Q): C col = lane&15 = q, row = (lane>>4)*4+reg = key.
// ---------------------------------------------------------------------------

template<int PHASE>
__device__ __forceinline__ void chunk_compute(
    int g, int ch, int lane, char* Pw,
    const bf16x8 (&qhf)[4][2], const bf16x8 (&qlf)[4][2],
    f32x4 (&O)[4][4], float (&lacc)[4], const float (&frc)[4],
    const int* SBL, const char* KhL, const char* VthL, const char* VtlL) {

    const int lr4 = lane >> 4;
    const int lc  = lane & 15;

    #pragma unroll
    for (int mt = 0; mt < 4; ++mt) {
        const int key = mt*16 + lc;
        const int ksw = (key & 7) << 4;
        bf16x8 ka0 = *(const bf16x8*)(KhL + ((key*128 +  0 + lr4*16) ^ ksw));
        bf16x8 ka1 = *(const bf16x8*)(KhL + ((key*128 + 64 + lr4*16) ^ ksw));
        int4 sb4;
        if (PHASE != 1) sb4 = *(const int4*)(SBL + ch*64 + mt*16 + lr4*4);
        #pragma unroll
        for (int qt = 0; qt < 4; ++qt) {
            f32x4 c = {0.f, 0.f, 0.f, 0.f};
            c = __builtin_amdgcn_mfma_f32_16x16x32_bf16(ka0, qhf[qt][0], c, 0, 0, 0);
            if (PHASE != 0)
                c = __builtin_amdgcn_mfma_f32_16x16x32_bf16(ka0, qlf[qt][0], c, 0, 0, 0);
            c = __builtin_amdgcn_mfma_f32_16x16x32_bf16(ka1, qhf[qt][1], c, 0, 0, 0);
            if (PHASE != 0)
                c = __builtin_amdgcn_mfma_f32_16x16x32_bf16(ka1, qlf[qt][1], c, 0, 0, 0);
            float e0 = __expf(c[0]*0.125f), e1 = __expf(c[1]*0.125f);
            float e2 = __expf(c[2]*0.125f), e3 = __expf(c[3]*0.125f);
            if (PHASE != 1) {
                if (sb4.x == g) e0 = 0.f;
                if (sb4.y == g) e1 = 0.f;
                if (sb4.z == g) e2 = 0.f;
                if (sb4.w == g) e3 = 0.f;
            }
            if (PHASE != 2) lacc[qt] += (e0+e1) + (e2+e3);
            if (PHASE == 2) {
                const float fr = frc[qt];
                e0 *= fr; e1 *= fr; e2 *= fr; e3 *= fr;
            }
            if (PHASE != 0) {
                uint2 w;
                w.x = (unsigned)f2bf(e0) | ((unsigned)f2bf(e1) << 16);
                w.y = (unsigned)f2bf(e2) | ((unsigned)f2bf(e3) << 16);
                const int qq = qt*16 + lc;
                *(uint2*)(Pw + ((qq*128 + mt*32 + lr4*8) ^ ((qq & 7) << 4))) = w;
            }
        }
    }

    if (PHASE != 0) {
        // PV: O += P * (Vh + Vl)
        bf16x8 pf[4][2];
        #pragma unroll
        for (int qt = 0; qt < 4; ++qt) {
            const int qq = qt*16 + lc;
            const int qsw = (qq & 7) << 4;
            pf[qt][0] = *(const bf16x8*)(Pw + ((qq*128 +  0 + lr4*16) ^ qsw));
            pf[qt][1] = *(const bf16x8*)(Pw + ((qq*128 + 64 + lr4*16) ^ qsw));
        }
        #pragma unroll
        for (int dt = 0; dt < 4; ++dt) {
            const int d = dt*16 + lc;
            const int dsw = (d & 7) << 4;
            bf16x8 vh0 = *(const bf16x8*)(VthL + ((d*128 +  0 + lr4*16) ^ dsw));
            bf16x8 vh1 = *(const bf16x8*)(VthL + ((d*128 + 64 + lr4*16) ^ dsw));
            bf16x8 vl0 = *(const bf16x8*)(VtlL + ((d*128 +  0 + lr4*16) ^ dsw));
            bf16x8 vl1 = *(const bf16x8*)(VtlL + ((d*128 + 64 + lr4*16) ^ dsw));
            #pragma unroll
            for (int qt = 0; qt < 4; ++qt) {
                O[qt][dt] = __builtin_amdgcn_mfma_f32_16x16x32_bf16(pf[qt][0], vh0, O[qt][dt], 0, 0, 0);
                O[qt][dt] = __builtin_amdgcn_mfma_f32_16x16x32_bf16(pf[qt][1], vh1, O[qt][dt], 0, 0, 0);
                O[qt][dt] = __builtin_amdgcn_mfma_f32_16x16x32_bf16(pf[qt][0], vl0, O[qt][dt], 0, 0, 0);
                O[qt][dt] = __builtin_amdgcn_mfma_f32_16x16x32_bf16(pf[qt][1], vl1, O[qt][dt], 0, 0, 0);
            }
        }
    }
}

__global__ __launch_bounds__(256, 2) void attn_kernel(const float* __restrict__ q,
                                                      const float* __restrict__ k,
                                                      const float* __restrict__ v,
                                                      const int* __restrict__ samp,
                                                      const int* __restrict__ qidx,
                                                      const int* __restrict__ kidx,
                                                      float* __restrict__ out) {
    __shared__ __align__(16) char KhL[8192];
    __shared__ __align__(16) char VthL[8192];
    __shared__ __align__(16) char VtlL[8192];
    __shared__ __align__(16) char PL[4][8192];
    __shared__ int qidxL[256];
    __shared__ int SPL[256];
    __shared__ int SBL[256];

    const int g = blockIdx.x, bh = blockIdx.y;
    const int tid = threadIdx.x;
    const int lane = tid & 63, w = tid >> 6;
    const int lr4 = lane >> 4, lc = lane & 15;
    const int kk = tid & 63, dc = tid >> 6;
    const size_t basef = (size_t)bh * NSEQ * DDIM;

    qidxL[tid] = qidx[bh*NSEQ + g*KBLK + tid];
    {
        int sp = samp[bh*NSAMP + tid];
        SPL[tid] = sp; SBL[tid] = sp >> 8;
    }
    __syncthreads();

    // Q fragments (hi/lo) in registers
    bf16x8 qhf[4][2], qlf[4][2];
    #pragma unroll
    for (int qt = 0; qt < 4; ++qt) {
        const int qrow = qidxL[w*64 + qt*16 + lc];
        const float* qp = q + basef + (size_t)qrow*DDIM;
        #pragma unroll
        for (int ks = 0; ks < 2; ++ks) {
            const float* p = qp + ks*32 + lr4*8;
            float4 a = *(const float4*)p;
            float4 b = *(const float4*)(p + 4);
            float xs[8] = {a.x,a.y,a.z,a.w,b.x,b.y,b.z,b.w};
            union { bf16x8 v; unsigned short s[8]; } hv, lv;
            #pragma unroll
            for (int e = 0; e < 8; ++e) {
                unsigned short h = f2bf(xs[e]);
                hv.s[e] = (short)h;
                lv.s[e] = (short)f2bf(xs[e] - bf2f(h));
            }
            qhf[qt][ks] = hv.v; qlf[qt][ks] = lv.v;
        }
    }

    f32x4 O[4][4];
    #pragma unroll
    for (int a = 0; a < 4; ++a)
        #pragma unroll
        for (int b = 0; b < 4; ++b) O[a][b] = (f32x4){0.f,0.f,0.f,0.f};
    float lb[4] = {0,0,0,0}, lr[4] = {0,0,0,0};
    float fdum[4] = {0,0,0,0};
    char* Pw = PL[w];

    // ---- PHASE A: residual l_res (1-split, K only) ----
    for (int ch = 0; ch < 4; ++ch) {
        __syncthreads();
        {
            const int korig = kidx[bh*NSEQ + SPL[ch*64 + kk]];
            const float* kr = k + basef + (size_t)korig*DDIM + dc*16;
            float4 f0 = ((const float4*)kr)[0], f1 = ((const float4*)kr)[1];
            float4 f2 = ((const float4*)kr)[2], f3 = ((const float4*)kr)[3];
            float xs[16] = {f0.x,f0.y,f0.z,f0.w,f1.x,f1.y,f1.z,f1.w,
                            f2.x,f2.y,f2.z,f2.w,f3.x,f3.y,f3.z,f3.w};
            union { bf16x8 v; unsigned short s[8]; } h0, h1;
            #pragma unroll
            for (int i = 0; i < 8; ++i) { h0.s[i] = (short)f2bf(xs[i]); h1.s[i] = (short)f2bf(xs[8+i]); }
            const int rb = kk*128 + dc*32, sw = (kk & 7) << 4;
            *(bf16x8*)(KhL + ((rb) ^ sw)) = h0.v;
            *(bf16x8*)(KhL + ((rb + 16) ^ sw)) = h1.v;
        }
        __syncthreads();
        chunk_compute<0>(g, ch, lane, Pw, qhf, qlf, O, lr, fdum, SBL, KhL, VthL, VtlL);
    }

    // ---- PHASE B: block-diagonal (2-split + PV) ----
    for (int ch = 0; ch < 4; ++ch) {
        __syncthreads();
        {
            const int korig = kidx[bh*NSEQ + g*KBLK + ch*64 + kk];
            const float* kr = k + basef + (size_t)korig*DDIM + dc*16;
            float4 f0 = ((const float4*)kr)[0], f1 = ((const float4*)kr)[1];
            float4 f2 = ((const float4*)kr)[2], f3 = ((const float4*)kr)[3];
            float xs[16] = {f0.x,f0.y,f0.z,f0.w,f1.x,f1.y,f1.z,f1.w,
                            f2.x,f2.y,f2.z,f2.w,f3.x,f3.y,f3.z,f3.w};
            union { bf16x8 v; unsigned short s[8]; } h0, h1;
            #pragma unroll
            for (int i = 0; i < 8; ++i) { h0.s[i] = (short)f2bf(xs[i]); h1.s[i] = (short)f2bf(xs[8+i]); }
            const int rb = kk*128 + dc*32, sw = (kk & 7) << 4;
            *(bf16x8*)(KhL + ((rb) ^ sw)) = h0.v;
            *(bf16x8*)(KhL + ((rb + 16) ^ sw)) = h1.v;

            const float* vr = v + basef + (size_t)korig*DDIM + dc*16;
            float4 g0 = ((const float4*)vr)[0], g1 = ((const float4*)vr)[1];
            float4 g2 = ((const float4*)vr)[2], g3 = ((const float4*)vr)[3];
            float ys[16] = {g0.x,g0.y,g0.z,g0.w,g1.x,g1.y,g1.z,g1.w,
                            g2.x,g2.y,g2.z,g2.w,g3.x,g3.y,g3.z,g3.w};
            #pragma unroll
            for (int i = 0; i < 16; ++i) {
                const int d = dc*16 + i;
                unsigned short h = f2bf(ys[i]);
                unsigned short lo = f2bf(ys[i] - bf2f(h));
                const int a = (d*128 + kk*2) ^ ((d & 7) << 4);
                *(short*)(VthL + a) = (short)h;
                *(short*)(VtlL + a) = (short)lo;
            }
        }
        __syncthreads();
        chunk_compute<1>(g, ch, lane, Pw, qhf, qlf, O, lb, fdum, SBL, KhL, VthL, VtlL);
    }

    // ---- reductions + mixing factors ----
    #pragma unroll
    for (int qt = 0; qt < 4; ++qt) {
        lb[qt] += __shfl_xor(lb[qt], 16, 64);
        lb[qt] += __shfl_xor(lb[qt], 32, 64);
        lr[qt] += __shfl_xor(lr[qt], 16, 64);
        lr[qt] += __shfl_xor(lr[qt], 32, 64);
    }
    float fbc[4], frc[4];
    #pragma unroll
    for (int qt = 0; qt < 4; ++qt) {
        const float lseb = __logf(lb[qt]);
        const float lser = __logf(lr[qt]) + 3.46573590279972f;  // + log(32)
        const float cm = 1.f / (1.f + __expf(lser - lseb));
        fbc[qt] = cm / lb[qt];
        frc[qt] = (1.f - cm) / lr[qt];
    }
    // scale O by row-mapped fb
    #pragma unroll
    for (int qt = 0; qt < 4; ++qt) {
        #pragma unroll
        for (int r = 0; r < 4; ++r) {
            const float f = __shfl(fbc[qt], (lane & 48) | (lr4*4 + r), 64);
            #pragma unroll
            for (int dt = 0; dt < 4; ++dt) O[qt][dt][r] *= f;
        }
    }

    // ---- PHASE C: residual full (P pre-scaled by fr) ----
    for (int ch = 0; ch < 4; ++ch) {
        __syncthreads();
        {
            const int korig = kidx[bh*NSEQ + SPL[ch*64 + kk]];
            const float* kr = k + basef + (size_t)korig*DDIM + dc*16;
            float4 f0 = ((const float4*)kr)[0], f1 = ((const float4*)kr)[1];
            float4 f2 = ((const float4*)kr)[2], f3 = ((const float4*)kr)[3];
            float xs[16] = {f0.x,f0.y,f0.z,f0.w,f1.x,f1.y,f1.z,f1.w,
                            f2.x,f2.y,f2.z,f2.w,f3.x,f3.y,f3.z,f3.w};
            union { bf16x8 v; unsigned short s[8]; } h0, h1;
            #pragma unroll
            for (int i = 0; i < 8; ++i) { h0.s[i] = (short)f2bf(xs[i]); h1.s[i] = (short)f2bf(xs[8+i]); }
            const int rb = kk*128 + dc*32, sw = (kk & 7) << 4;
            *(bf16x8*)(KhL + ((rb) ^ sw)) = h0.v;
            *(bf16x8*)(KhL + ((rb + 16) ^ sw)) = h1.v;

            const float* vr = v + basef + (size_t)korig*DDIM + dc*16;
            float4 g0 = ((const float4*)vr)[0], g1 = ((const float4*)vr)[1];
            float4 g2 = ((const float4*)vr)[2], g3 = ((const float4*)vr)[3];
            float ys[16] = {g0.x,g0.y,g0.z,g0.w,g1.x,g1.y,g1.z,g1.w,
                            g2.x,g2.y,g2.z,g2.w,g3.x,g3.y,g3.z,g3.w};
            #pragma unroll
            for (int i = 0; i < 16; ++i) {
                const int d = dc*16 + i;
                unsigned short h = f2bf(ys[i]);
                unsigned short lo = f2bf(ys[i] - bf2f(h));
                const int a = (d*128 + kk*2) ^ ((d & 7) << 4);
                *(short*)(VthL + a) = (short)h;
                *(short*)(VtlL + a) = (short)lo;
            }
        }
        __syncthreads();
        chunk_compute<2>(g, ch, lane, Pw, qhf, qlf, O, lb, frc, SBL, KhL, VthL, VtlL);
    }

    // ---- epilogue: write at original query rows ----
    float* ob = out + basef;
    #pragma unroll
    for (int qt = 0; qt < 4; ++qt) {
        #pragma unroll
        for (int r = 0; r < 4; ++r) {
            const int orow = qidxL[w*64 + qt*16 + lr4*4 + r];
            float* p = ob + (size_t)orow*DDIM + lc;
            #pragma unroll
            for (int dt = 0; dt < 4; ++dt) p[dt*16] = O[qt][dt][r];
        }
    }
}

// ---------------------------------------------------------------------------
extern "C" void kernel_launch(void* const* d_in, const int* in_sizes, int n_in,
                              void* d_out, int out_size, void* d_ws, size_t ws_size,
                              hipStream_t stream) {
    const float* q    = (const float*)d_in[0];
    const float* k    = (const float*)d_in[1];
    const float* v    = (const float*)d_in[2];
    const float* pd   = (const float*)d_in[3];
    const int*   samp = (const int*)d_in[4];
    float* out = (float*)d_out;

    char* ws = (char*)d_ws;
    float*         knorm = (float*)(ws + 0);
    float*         kmax  = (float*)(ws + 1048576);
    unsigned char* qh    = (unsigned char*)(ws + 1048704);
    unsigned char* kh    = (unsigned char*)(ws + 1310848);
    int*           qidx  = (int*)(ws + 1572992);
    int*           kidx  = (int*)(ws + 2621568);

    hipLaunchKernelGGL(knorm_kernel, dim3(NBH), dim3(256), 0, stream, k, knorm, kmax);
    hipLaunchKernelGGL(hash_kernel, dim3(NBH*NSEQ/256), dim3(256), 0, stream,
                       q, k, pd, knorm, kmax, qh, kh);
    hipLaunchKernelGGL(sort_kernel, dim3(NBH), dim3(128), 0, stream, qh, qidx);
    hipLaunchKernelGGL(sort_kernel, dim3(NBH), dim3(128), 0, stream, kh, kidx);
    hipLaunchKernelGGL(attn_kernel, dim3(NB, NBH), dim3(256), 0, stream,
                       q, k, v, samp, qidx, kidx, out);
}

// Round 3
// 234.004 us; speedup vs baseline: 13.5508x; 1.4360x over previous
//
#include <hip/hip_runtime.h>
#include <hip/hip_bf16.h>
#include <math.h>

#define BD 2
#define HD 16
#define NSEQ 8192
#define DDIM 64
#define NPROJ 7
#define KBLK 256
#define NSAMP 256
#define NBH (BD*HD)           // 32
#define NB (NSEQ/KBLK)        // 32

typedef short bf16x8 __attribute__((ext_vector_type(8)));
typedef float f32x4 __attribute__((ext_vector_type(4)));

// pack two f32 -> u32 of 2 bf16 (RTNE via v_cvt_pk_bf16_f32)
__device__ __forceinline__ unsigned int pk2bf(float a, float b) {
    union { __hip_bfloat162 h; unsigned int u; } t;
    t.h = __float22bfloat162_rn(make_float2(a, b));
    return t.u;
}
__device__ __forceinline__ unsigned short f2bf1(float a) {
    union { __hip_bfloat16 h; unsigned short u; } t;
    t.h = __float2bfloat16(a);
    return t.u;
}
__device__ __forceinline__ float bf2f(unsigned short h) {
    union { float f; unsigned int u; } x; x.u = ((unsigned int)h) << 16;
    return x.f;
}

// ---------------------------------------------------------------------------
// Kernel A: per-key norms + per-(b,h) max norm (256 blocks, atomicMax on bits)
// ---------------------------------------------------------------------------
__global__ __launch_bounds__(256) void knorm_kernel(const float* __restrict__ key,
                                                    float* __restrict__ knorm,
                                                    unsigned int* __restrict__ kmax_bits) {
    const int blk = blockIdx.x;          // 32 bh * 8 segments
    const int bh = blk >> 3;
    const int seg = blk & 7;
    const int tid = threadIdx.x;
    __shared__ float red[256];
    float lmax = 0.f;
    const float* kb = key + (size_t)bh * NSEQ * DDIM;
    const int n0 = seg * 1024;
    for (int n = n0 + tid; n < n0 + 1024; n += 256) {
        const float4* kp = (const float4*)(kb + (size_t)n * DDIM);
        float ss = 0.f;
        #pragma unroll
        for (int j = 0; j < 16; ++j) {
            float4 t = kp[j];
            ss += t.x*t.x + t.y*t.y + t.z*t.z + t.w*t.w;
        }
        float nr = sqrtf(ss);
        knorm[bh*NSEQ + n] = nr;
        lmax = fmaxf(lmax, nr);
    }
    red[tid] = lmax;
    __syncthreads();
    for (int s = 128; s > 0; s >>= 1) {
        if (tid < s) red[tid] = fmaxf(red[tid], red[tid+s]);
        __syncthreads();
    }
    if (tid == 0) atomicMax(&kmax_bits[bh], __float_as_uint(red[0]));
}

// ---------------------------------------------------------------------------
// Kernel B: LSH hashes (identical dot accumulation order to the passing v2)
// ---------------------------------------------------------------------------
__global__ __launch_bounds__(256) void hash_kernel(const float* __restrict__ q,
                                                   const float* __restrict__ k,
                                                   const float* __restrict__ pd,
                                                   const float* __restrict__ knorm,
                                                   const unsigned int* __restrict__ kmax_bits,
                                                   unsigned char* __restrict__ qh,
                                                   unsigned char* __restrict__ kh) {
    __shared__ float pds[(DDIM+1)*NPROJ];
    const int tid = threadIdx.x;
    for (int i = tid; i < (DDIM+1)*NPROJ; i += 256) pds[i] = pd[i];
    __syncthreads();

    const int lin = blockIdx.x * 256 + tid;
    const int bh = lin / NSEQ;

    float acc[NPROJ];
    float4 xv[16];

    {
        const float4* xp = (const float4*)(q + (size_t)lin * DDIM);
        #pragma unroll
        for (int j = 0; j < 16; ++j) xv[j] = xp[j];
        #pragma unroll
        for (int r = 0; r < NPROJ; ++r) acc[r] = 0.f;
        #pragma unroll
        for (int j = 0; j < 16; ++j) {
            float xs[4] = {xv[j].x, xv[j].y, xv[j].z, xv[j].w};
            #pragma unroll
            for (int c = 0; c < 4; ++c) {
                const int d = j*4 + c;
                #pragma unroll
                for (int r = 0; r < NPROJ; ++r) acc[r] += xs[c] * pds[d*NPROJ + r];
            }
        }
        int bin = 0;
        #pragma unroll
        for (int r = 0; r < NPROJ; ++r) bin |= (acc[r] > 0.f) << r;
        qh[lin] = (unsigned char)(bin ^ (bin >> 1));
    }

    {
        const float4* xp = (const float4*)(k + (size_t)lin * DDIM);
        #pragma unroll
        for (int j = 0; j < 16; ++j) xv[j] = xp[j];
        #pragma unroll
        for (int r = 0; r < NPROJ; ++r) acc[r] = 0.f;
        #pragma unroll
        for (int j = 0; j < 16; ++j) {
            float xs[4] = {xv[j].x, xv[j].y, xv[j].z, xv[j].w};
            #pragma unroll
            for (int c = 0; c < 4; ++c) {
                const int d = j*4 + c;
                #pragma unroll
                for (int r = 0; r < NPROJ; ++r) acc[r] += xs[c] * pds[d*NPROJ + r];
            }
        }
        const float kn = knorm[lin];
        const float km = __uint_as_float(kmax_bits[bh]);
        const float ex = sqrtf(fmaxf(km*km - kn*kn, 0.f));
        #pragma unroll
        for (int r = 0; r < NPROJ; ++r) acc[r] += ex * pds[DDIM*NPROJ + r];
        int bin = 0;
        #pragma unroll
        for (int r = 0; r < NPROJ; ++r) bin |= (acc[r] > 0.f) << r;
        kh[lin] = (unsigned char)(bin ^ (bin >> 1));
    }
}

// ---------------------------------------------------------------------------
// Kernel C: parallel stable counting sort (128 buckets); grid (32 bh, 2 arrays)
// ---------------------------------------------------------------------------
__global__ __launch_bounds__(128) void sort_kernel(const unsigned char* __restrict__ qhash,
                                                   const unsigned char* __restrict__ khash,
                                                   int* __restrict__ qidx,
                                                   int* __restrict__ kidx) {
    __shared__ unsigned char hsh[NSEQ];
    __shared__ unsigned short cnt[128][128];
    __shared__ int base[128];
    const int bh = blockIdx.x, tid = threadIdx.x;
    const unsigned char* hash = blockIdx.y ? khash : qhash;
    int* idx = blockIdx.y ? kidx : qidx;
    const unsigned int* src = (const unsigned int*)(hash + (size_t)bh * NSEQ);
    for (int i = tid; i < NSEQ/4; i += 128) ((unsigned int*)hsh)[i] = src[i];
    for (int b = 0; b < 128; ++b) cnt[tid][b] = 0;
    __syncthreads();
    {
        const unsigned char* s = hsh + tid*64;
        for (int i = 0; i < 64; ++i) cnt[tid][s[i]]++;
    }
    __syncthreads();
    {
        int run = 0;
        for (int s = 0; s < 128; ++s) {
            int t = cnt[s][tid]; cnt[s][tid] = (unsigned short)run; run += t;
        }
        base[tid] = run;
    }
    __syncthreads();
    if (tid == 0) {
        int run = 0;
        for (int b = 0; b < 128; ++b) { int t = base[b]; base[b] = run; run += t; }
    }
    __syncthreads();
    {
        const unsigned char* s = hsh + tid*64;
        int* dst = idx + (size_t)bh * NSEQ;
        for (int i = 0; i < 64; ++i) {
            int h = s[i];
            int c = cnt[tid][h];
            cnt[tid][h] = (unsigned short)(c + 1);
            dst[base[h] + c] = tid*64 + i;
        }
    }
}

// ---------------------------------------------------------------------------
// Kernel D: MFMA fused attention, 2 phases (block-diag, residual x32).
//   out = (Sum_blk e*v + 32*Sum_res e*v) / (l_blk + 32*l_res)
// (exact identity of the reference's log-space merge; 32 = N/SAMPLE folds
//  into the exp2 bias: exp(s)*32 = exp2(s*log2e + 5))
// ---------------------------------------------------------------------------

#define LOG2E_8 0.18033688011112042f   // log2(e)/8

template<int PHASE>   // 0 = block-diagonal, 1 = residual (x32, masked)
__device__ __forceinline__ void chunk_compute(
    int g, int ch, int lane, char* Pw,
    const bf16x8 (&qhf)[4][2], const bf16x8 (&qlf)[4][2],
    f32x4 (&O)[4][4], float (&lacc)[4],
    const int* SBL, const char* KhL, const char* VthL, const char* VtlL) {

    const int lr4 = lane >> 4;
    const int lc  = lane & 15;

    #pragma unroll
    for (int mt = 0; mt < 4; ++mt) {
        const int key = mt*16 + lc;
        const int ksw = (key & 7) << 4;
        bf16x8 ka0 = *(const bf16x8*)(KhL + ((key*128 +  0 + lr4*16) ^ ksw));
        bf16x8 ka1 = *(const bf16x8*)(KhL + ((key*128 + 64 + lr4*16) ^ ksw));
        int4 sb4;
        if (PHASE) sb4 = *(const int4*)(SBL + ch*64 + mt*16 + lr4*4);
        #pragma unroll
        for (int qt = 0; qt < 4; ++qt) {
            f32x4 c = {0.f, 0.f, 0.f, 0.f};
            c = __builtin_amdgcn_mfma_f32_16x16x32_bf16(ka0, qhf[qt][0], c, 0, 0, 0);
            c = __builtin_amdgcn_mfma_f32_16x16x32_bf16(ka0, qlf[qt][0], c, 0, 0, 0);
            c = __builtin_amdgcn_mfma_f32_16x16x32_bf16(ka1, qhf[qt][1], c, 0, 0, 0);
            c = __builtin_amdgcn_mfma_f32_16x16x32_bf16(ka1, qlf[qt][1], c, 0, 0, 0);
            const float bias = PHASE ? 5.0f : 0.0f;   // log2(32)
            float e0 = exp2f(fmaf(c[0], LOG2E_8, bias));
            float e1 = exp2f(fmaf(c[1], LOG2E_8, bias));
            float e2 = exp2f(fmaf(c[2], LOG2E_8, bias));
            float e3 = exp2f(fmaf(c[3], LOG2E_8, bias));
            if (PHASE) {
                if (sb4.x == g) e0 = 0.f;
                if (sb4.y == g) e1 = 0.f;
                if (sb4.z == g) e2 = 0.f;
                if (sb4.w == g) e3 = 0.f;
            }
            lacc[qt] += (e0+e1) + (e2+e3);
            uint2 w;
            w.x = pk2bf(e0, e1);
            w.y = pk2bf(e2, e3);
            const int qq = qt*16 + lc;
            *(uint2*)(Pw + ((qq*128 + mt*32 + lr4*8) ^ ((qq & 7) << 4))) = w;
        }
    }

    // PV: O += P * (Vh + Vl)
    bf16x8 pf[4][2];
    #pragma unroll
    for (int qt = 0; qt < 4; ++qt) {
        const int qq = qt*16 + lc;
        const int qsw = (qq & 7) << 4;
        pf[qt][0] = *(const bf16x8*)(Pw + ((qq*128 +  0 + lr4*16) ^ qsw));
        pf[qt][1] = *(const bf16x8*)(Pw + ((qq*128 + 64 + lr4*16) ^ qsw));
    }
    #pragma unroll
    for (int dt = 0; dt < 4; ++dt) {
        const int d = dt*16 + lc;
        const int dsw = (d & 7) << 4;
        bf16x8 vh0 = *(const bf16x8*)(VthL + ((d*128 +  0 + lr4*16) ^ dsw));
        bf16x8 vh1 = *(const bf16x8*)(VthL + ((d*128 + 64 + lr4*16) ^ dsw));
        bf16x8 vl0 = *(const bf16x8*)(VtlL + ((d*128 +  0 + lr4*16) ^ dsw));
        bf16x8 vl1 = *(const bf16x8*)(VtlL + ((d*128 + 64 + lr4*16) ^ dsw));
        #pragma unroll
        for (int qt = 0; qt < 4; ++qt) {
            O[qt][dt] = __builtin_amdgcn_mfma_f32_16x16x32_bf16(pf[qt][0], vh0, O[qt][dt], 0, 0, 0);
            O[qt][dt] = __builtin_amdgcn_mfma_f32_16x16x32_bf16(pf[qt][1], vh1, O[qt][dt], 0, 0, 0);
            O[qt][dt] = __builtin_amdgcn_mfma_f32_16x16x32_bf16(pf[qt][0], vl0, O[qt][dt], 0, 0, 0);
            O[qt][dt] = __builtin_amdgcn_mfma_f32_16x16x32_bf16(pf[qt][1], vl1, O[qt][dt], 0, 0, 0);
        }
    }
}

__global__ __launch_bounds__(256, 2) void attn_kernel(const float* __restrict__ q,
                                                      const float* __restrict__ k,
                                                      const float* __restrict__ v,
                                                      const int* __restrict__ samp,
                                                      const int* __restrict__ qidx,
                                                      const int* __restrict__ kidx,
                                                      float* __restrict__ out) {
    __shared__ __align__(16) char KhL[8192];
    __shared__ __align__(16) char VthL[8192];
    __shared__ __align__(16) char VtlL[8192];
    __shared__ __align__(16) char PL[4][8192];
    __shared__ int qidxL[256];
    __shared__ int SPL[256];
    __shared__ int SBL[256];

    const int g = blockIdx.x, bh = blockIdx.y;
    const int tid = threadIdx.x;
    const int lane = tid & 63, w = tid >> 6;
    const int lr4 = lane >> 4, lc = lane & 15;
    const int kk = tid & 63, dc = tid >> 6;
    const size_t basef = (size_t)bh * NSEQ * DDIM;

    qidxL[tid] = qidx[bh*NSEQ + g*KBLK + tid];
    {
        int sp = samp[bh*NSAMP + tid];
        SPL[tid] = sp; SBL[tid] = sp >> 8;
    }
    __syncthreads();

    // Q fragments (hi/lo) in registers
    bf16x8 qhf[4][2], qlf[4][2];
    #pragma unroll
    for (int qt = 0; qt < 4; ++qt) {
        const int qrow = qidxL[w*64 + qt*16 + lc];
        const float* qp = q + basef + (size_t)qrow*DDIM;
        #pragma unroll
        for (int ks = 0; ks < 2; ++ks) {
            const float* p = qp + ks*32 + lr4*8;
            float4 a = *(const float4*)p;
            float4 b = *(const float4*)(p + 4);
            float xs[8] = {a.x,a.y,a.z,a.w,b.x,b.y,b.z,b.w};
            union { bf16x8 v; unsigned int u[4]; } hv, lv;
            #pragma unroll
            for (int j = 0; j < 4; ++j) {
                __hip_bfloat162 hp = __float22bfloat162_rn(make_float2(xs[2*j], xs[2*j+1]));
                union { __hip_bfloat162 h; unsigned int u; } tc; tc.h = hp;
                hv.u[j] = tc.u;
                float l0 = xs[2*j]   - __low2float(hp);
                float l1 = xs[2*j+1] - __high2float(hp);
                lv.u[j] = pk2bf(l0, l1);
            }
            qhf[qt][ks] = hv.v; qlf[qt][ks] = lv.v;
        }
    }

    f32x4 O[4][4];
    #pragma unroll
    for (int a = 0; a < 4; ++a)
        #pragma unroll
        for (int b = 0; b < 4; ++b) O[a][b] = (f32x4){0.f,0.f,0.f,0.f};
    float lacc[4] = {0,0,0,0};
    char* Pw = PL[w];

    // ==== PHASE 0: block-diagonal ====
    for (int ch = 0; ch < 4; ++ch) {
        __syncthreads();
        {
            const int korig = kidx[bh*NSEQ + g*KBLK + ch*64 + kk];
            const float* kr = k + basef + (size_t)korig*DDIM + dc*16;
            float4 f0 = ((const float4*)kr)[0], f1 = ((const float4*)kr)[1];
            float4 f2 = ((const float4*)kr)[2], f3 = ((const float4*)kr)[3];
            union { bf16x8 v; unsigned int u[4]; } h0, h1;
            h0.u[0] = pk2bf(f0.x,f0.y); h0.u[1] = pk2bf(f0.z,f0.w);
            h0.u[2] = pk2bf(f1.x,f1.y); h0.u[3] = pk2bf(f1.z,f1.w);
            h1.u[0] = pk2bf(f2.x,f2.y); h1.u[1] = pk2bf(f2.z,f2.w);
            h1.u[2] = pk2bf(f3.x,f3.y); h1.u[3] = pk2bf(f3.z,f3.w);
            const int rb = kk*128 + dc*32, sw = (kk & 7) << 4;
            *(bf16x8*)(KhL + ((rb) ^ sw)) = h0.v;
            *(bf16x8*)(KhL + ((rb + 16) ^ sw)) = h1.v;

            const float* vr = v + basef + (size_t)korig*DDIM + dc*16;
            float4 g0 = ((const float4*)vr)[0], g1 = ((const float4*)vr)[1];
            float4 g2 = ((const float4*)vr)[2], g3 = ((const float4*)vr)[3];
            float ys[16] = {g0.x,g0.y,g0.z,g0.w,g1.x,g1.y,g1.z,g1.w,
                            g2.x,g2.y,g2.z,g2.w,g3.x,g3.y,g3.z,g3.w};
            #pragma unroll
            for (int i = 0; i < 16; ++i) {
                const int d = dc*16 + i;
                unsigned short h = f2bf1(ys[i]);
                unsigned short lo = f2bf1(ys[i] - bf2f(h));
                const int a = (d*128 + kk*2) ^ ((d & 7) << 4);
                *(short*)(VthL + a) = (short)h;
                *(short*)(VtlL + a) = (short)lo;
            }
        }
        __syncthreads();
        chunk_compute<0>(g, ch, lane, Pw, qhf, qlf, O, lacc, SBL, KhL, VthL, VtlL);
    }

    // ==== PHASE 1: residual (sampled columns, x32, masked) ====
    for (int ch = 0; ch < 4; ++ch) {
        __syncthreads();
        {
            const int korig = kidx[bh*NSEQ + SPL[ch*64 + kk]];
            const float* kr = k + basef + (size_t)korig*DDIM + dc*16;
            float4 f0 = ((const float4*)kr)[0], f1 = ((const float4*)kr)[1];
            float4 f2 = ((const float4*)kr)[2], f3 = ((const float4*)kr)[3];
            union { bf16x8 v; unsigned int u[4]; } h0, h1;
            h0.u[0] = pk2bf(f0.x,f0.y); h0.u[1] = pk2bf(f0.z,f0.w);
            h0.u[2] = pk2bf(f1.x,f1.y); h0.u[3] = pk2bf(f1.z,f1.w);
            h1.u[0] = pk2bf(f2.x,f2.y); h1.u[1] = pk2bf(f2.z,f2.w);
            h1.u[2] = pk2bf(f3.x,f3.y); h1.u[3] = pk2bf(f3.z,f3.w);
            const int rb = kk*128 + dc*32, sw = (kk & 7) << 4;
            *(bf16x8*)(KhL + ((rb) ^ sw)) = h0.v;
            *(bf16x8*)(KhL + ((rb + 16) ^ sw)) = h1.v;

            const float* vr = v + basef + (size_t)korig*DDIM + dc*16;
            float4 g0 = ((const float4*)vr)[0], g1 = ((const float4*)vr)[1];
            float4 g2 = ((const float4*)vr)[2], g3 = ((const float4*)vr)[3];
            float ys[16] = {g0.x,g0.y,g0.z,g0.w,g1.x,g1.y,g1.z,g1.w,
                            g2.x,g2.y,g2.z,g2.w,g3.x,g3.y,g3.z,g3.w};
            #pragma unroll
            for (int i = 0; i < 16; ++i) {
                const int d = dc*16 + i;
                unsigned short h = f2bf1(ys[i]);
                unsigned short lo = f2bf1(ys[i] - bf2f(h));
                const int a = (d*128 + kk*2) ^ ((d & 7) << 4);
                *(short*)(VthL + a) = (short)h;
                *(short*)(VtlL + a) = (short)lo;
            }
        }
        __syncthreads();
        chunk_compute<1>(g, ch, lane, Pw, qhf, qlf, O, lacc, SBL, KhL, VthL, VtlL);
    }

    // ---- epilogue: normalize and write at original query rows ----
    #pragma unroll
    for (int qt = 0; qt < 4; ++qt) {
        lacc[qt] += __shfl_xor(lacc[qt], 16, 64);
        lacc[qt] += __shfl_xor(lacc[qt], 32, 64);
        lacc[qt] = 1.f / lacc[qt];
    }
    float* ob = out + basef;
    #pragma unroll
    for (int qt = 0; qt < 4; ++qt) {
        #pragma unroll
        for (int r = 0; r < 4; ++r) {
            const float f = __shfl(lacc[qt], (lane & 48) | (lr4*4 + r), 64);
            const int orow = qidxL[w*64 + qt*16 + lr4*4 + r];
            float* p = ob + (size_t)orow*DDIM + lc;
            #pragma unroll
            for (int dt = 0; dt < 4; ++dt) p[dt*16] = O[qt][dt][r] * f;
        }
    }
}

// ---------------------------------------------------------------------------
extern "C" void kernel_launch(void* const* d_in, const int* in_sizes, int n_in,
                              void* d_out, int out_size, void* d_ws, size_t ws_size,
                              hipStream_t stream) {
    const float* q    = (const float*)d_in[0];
    const float* k    = (const float*)d_in[1];
    const float* v    = (const float*)d_in[2];
    const float* pd   = (const float*)d_in[3];
    const int*   samp = (const int*)d_in[4];
    float* out = (float*)d_out;

    char* ws = (char*)d_ws;
    float*         knorm = (float*)(ws + 0);
    unsigned int*  kmaxb = (unsigned int*)(ws + 1048576);
    unsigned char* qh    = (unsigned char*)(ws + 1048704);
    unsigned char* kh    = (unsigned char*)(ws + 1310848);
    int*           qidx  = (int*)(ws + 1572992);
    int*           kidx  = (int*)(ws + 2621568);

    hipMemsetAsync(kmaxb, 0, NBH*sizeof(unsigned int), stream);
    hipLaunchKernelGGL(knorm_kernel, dim3(256), dim3(256), 0, stream, k, knorm, kmaxb);
    hipLaunchKernelGGL(hash_kernel, dim3(NBH*NSEQ/256), dim3(256), 0, stream,
                       q, k, pd, knorm, kmaxb, qh, kh);
    hipLaunchKernelGGL(sort_kernel, dim3(NBH, 2), dim3(128), 0, stream, qh, kh, qidx, kidx);
    hipLaunchKernelGGL(attn_kernel, dim3(NB, NBH), dim3(256), 0, stream,
                       q, k, v, samp, qidx, kidx, out);
}